// Round 4
// baseline (666.609 us; speedup 1.0000x reference)
//
#include <hip/hip_runtime.h>
#include <hip/hip_bf16.h>
#include <stdint.h>

#define THREADS 512

typedef __bf16 bf16x8 __attribute__((ext_vector_type(8)));
typedef float f32x4 __attribute__((ext_vector_type(4)));

// workspace layout (bytes)
#define WS_WS_OFF    0                             // Ws hi bf16 [512][512]
#define WS_WINH_OFF  (512*512*2)                   // w_in hi bf16 [512][256]
#define WS_WINL_OFF  (WS_WINH_OFF + 512*256*2)     // w_in lo bf16 [512][256]
#define WS_WOUTH_OFF (WS_WINL_OFF + 512*256*2)     // w_out hi bf16 [256][512]
#define WS_WOUTL_OFF (WS_WOUTH_OFF + 256*512*2)    // w_out lo bf16 [256][512]
#define WS_CVEC_OFF  (WS_WOUTL_OFF + 256*512*2)    // f32 [512] = w_in_b + b

__device__ __forceinline__ unsigned short f2bf(float f) {
  union { float f; unsigned int u; } v; v.f = f;
  unsigned int r = (v.u + 0x7fffu + ((v.u >> 16) & 1u)) >> 16;  // RTNE
  return (unsigned short)r;
}
__device__ __forceinline__ float bf2f(unsigned short h) {
  union { unsigned int u; float f; } v; v.u = ((unsigned int)h) << 16;
  return v.f;
}

__device__ __forceinline__ void gload16(const void* g, void* l) {
  __builtin_amdgcn_global_load_lds(
      (const __attribute__((address_space(1))) unsigned int*)g,
      (__attribute__((address_space(3))) unsigned int*)l,
      16, 0, 0);
}

__global__ void prep_kernel(const float* __restrict__ W,
                            const float* __restrict__ w_in_w,
                            const float* __restrict__ w_out_w,
                            const float* __restrict__ w_in_b,
                            const float* __restrict__ bvec,
                            unsigned char* __restrict__ ws) {
  int i = blockIdx.x * blockDim.x + threadIdx.x;
  unsigned short* Wsb   = (unsigned short*)(ws + WS_WS_OFF);
  unsigned short* WinH  = (unsigned short*)(ws + WS_WINH_OFF);
  unsigned short* WinL  = (unsigned short*)(ws + WS_WINL_OFF);
  unsigned short* WoutH = (unsigned short*)(ws + WS_WOUTH_OFF);
  unsigned short* WoutL = (unsigned short*)(ws + WS_WOUTL_OFF);
  float* cvec = (float*)(ws + WS_CVEC_OFF);
  if (i < 512*512) {
    int r = i >> 9, c = i & 511;
    Wsb[i] = f2bf(0.5f * (W[i] + W[c*512 + r]));   // symmetrize in f32, then cast
  } else if (i < 512*512 + 512*256) {
    int j = i - 512*512;
    float w = w_in_w[j];
    unsigned short h = f2bf(w);
    WinH[j] = h;
    WinL[j] = f2bf(w - bf2f(h));
  } else if (i < 512*512 + 512*256 + 256*512) {
    int j = i - 512*512 - 512*256;
    float w = w_out_w[j];
    unsigned short h = f2bf(w);
    WoutH[j] = h;
    WoutL[j] = f2bf(w - bf2f(h));
  } else if (i < 512*512 + 512*256 + 256*512 + 512) {
    int j = i - 512*512 - 512*256 - 256*512;
    cvec[j] = w_in_b[j] + bvec[j];
  }
}

// Block: 512 threads = 8 waves (2 m-slices x 4 n-slices), owns 64 rows.
// LDS 128KB: region A (64KB: recurrent a-tile [64][512] bf16; input phase xh/xl
// [64][256] each) + T region (64KB: 2x32KB weight buffers). All linear (no swizzle).
__global__ void __launch_bounds__(THREADS, 2)
attractor_kernel(const float* __restrict__ x,
                 const unsigned char* __restrict__ ws,
                 const float* __restrict__ w_out_b,
                 float* __restrict__ out) {
  __shared__ unsigned char smem[131072];
  unsigned char* Albase = smem;           // 64KB
  unsigned char* Axh    = smem;           // input phase: xh [64][256] (32KB)
  unsigned char* Axl    = smem + 32768;   // input phase: xl [64][256] (32KB)
  unsigned char* Tbuf0  = smem + 65536;   // 32KB
  unsigned char* Tbuf1  = smem + 98304;   // 32KB

  const int tid  = threadIdx.x;
  const int lane = tid & 63;
  const int l15  = lane & 15;
  const int l4   = lane >> 4;
  const int wave = tid >> 6;
  const int wm   = wave >> 2;   // 0..1  (m-slice of 32 rows)
  const int wn   = wave & 3;    // 0..3  (n-slice of 128 cols)
  const int m0   = blockIdx.x * 64;

  const unsigned char* gWs    = ws + WS_WS_OFF;
  const unsigned char* gWinH  = ws + WS_WINH_OFF;
  const unsigned char* gWinL  = ws + WS_WINL_OFF;
  const unsigned char* gWoutH = ws + WS_WOUTH_OFF;
  const unsigned char* gWoutL = ws + WS_WOUTL_OFF;
  const float* cvec = (const float*)(ws + WS_CVEC_OFF);

  // ---- stage x tile (64x256 f32) -> xh/xl bf16 tiles (linear, 512B rows) ----
  {
    const float4* xt = (const float4*)(x + (size_t)m0 * 256);
#pragma unroll
    for (int p = 0; p < 8; ++p) {
      int i = tid + p * THREADS;          // 0..4095 float4 chunks
      float4 v = xt[i];
      int m  = i >> 6;
      int bc = (i & 63) * 8;              // bf16 byte col within 512B row
      unsigned short hx = f2bf(v.x), hy = f2bf(v.y), hz = f2bf(v.z), hw = f2bf(v.w);
      unsigned short lx = f2bf(v.x - bf2f(hx)), ly = f2bf(v.y - bf2f(hy));
      unsigned short lz = f2bf(v.z - bf2f(hz)), lw = f2bf(v.w - bf2f(hw));
      *(uint2*)(Axh + m * 512 + bc) =
          make_uint2((unsigned int)hx | ((unsigned int)hy << 16),
                     (unsigned int)hz | ((unsigned int)hw << 16));
      *(uint2*)(Axl + m * 512 + bc) =
          make_uint2((unsigned int)lx | ((unsigned int)ly << 16),
                     (unsigned int)lz | ((unsigned int)lw << 16));
    }
  }

  // ---- accumulators init with combined bias (w_in_b + b) ----
  f32x4 acc[2][8];
#pragma unroll
  for (int nf = 0; nf < 8; ++nf) {
    float cv = cvec[wn * 128 + nf * 16 + l15];
    f32x4 v = {cv, cv, cv, cv};
    acc[0][nf] = v;
    acc[1][nf] = v;
  }

  // ---- phase A: c = x @ w_in^T, split bf16 (xh*Wh + xh*Wl + xl*Wh), K=256 ----
#pragma unroll 1
  for (int ks = 0; ks < 8; ++ks) {
    __syncthreads();   // previous step's reads of Tbufs done
    for (int c = tid; c < 2048; c += THREADS) {
      int d = c << 4; int row = d >> 6; int col = d & 63;
      size_t g = (size_t)row * 512 + (size_t)ks * 64 + col;
      gload16(gWinH + g, Tbuf0 + d);
      gload16(gWinL + g, Tbuf1 + d);
    }
    __syncthreads();   // staging (and, at ks=0, x-tile writes) visible
    int akb = ks * 64 + l4 * 16;
    bf16x8 xh0 = *(const bf16x8*)(Axh + (wm*32      + l15) * 512 + akb);
    bf16x8 xh1 = *(const bf16x8*)(Axh + (wm*32 + 16 + l15) * 512 + akb);
    bf16x8 xl0 = *(const bf16x8*)(Axl + (wm*32      + l15) * 512 + akb);
    bf16x8 xl1 = *(const bf16x8*)(Axl + (wm*32 + 16 + l15) * 512 + akb);
#pragma unroll
    for (int nf = 0; nf < 8; ++nf) {
      int bp = (wn*128 + nf*16 + l15) * 64 + l4 * 16;
      bf16x8 bh = *(const bf16x8*)(Tbuf0 + bp);
      bf16x8 bl = *(const bf16x8*)(Tbuf1 + bp);
      acc[0][nf] = __builtin_amdgcn_mfma_f32_16x16x32_bf16(xh0, bh, acc[0][nf], 0, 0, 0);
      acc[0][nf] = __builtin_amdgcn_mfma_f32_16x16x32_bf16(xh0, bl, acc[0][nf], 0, 0, 0);
      acc[0][nf] = __builtin_amdgcn_mfma_f32_16x16x32_bf16(xl0, bh, acc[0][nf], 0, 0, 0);
      acc[1][nf] = __builtin_amdgcn_mfma_f32_16x16x32_bf16(xh1, bh, acc[1][nf], 0, 0, 0);
      acc[1][nf] = __builtin_amdgcn_mfma_f32_16x16x32_bf16(xh1, bl, acc[1][nf], 0, 0, 0);
      acc[1][nf] = __builtin_amdgcn_mfma_f32_16x16x32_bf16(xl1, bh, acc[1][nf], 0, 0, 0);
    }
  }
  __syncthreads();

  // keep C = c + biases in registers for all iterations
  f32x4 cfrag[2][8];
#pragma unroll
  for (int mf = 0; mf < 2; ++mf)
#pragma unroll
    for (int nf = 0; nf < 8; ++nf)
      cfrag[mf][nf] = acc[mf][nf];

  // a = tanh(acc) -> A_lds (bf16, linear [64][512], 1024B rows).
  // C/D frag: col=l15, row=l4*4+r.
  auto write_a = [&]() {
#pragma unroll
    for (int mf = 0; mf < 2; ++mf) {
#pragma unroll
      for (int nf = 0; nf < 8; ++nf) {
        int n2 = (wn*128 + nf*16 + l15) * 2;
#pragma unroll
        for (int r = 0; r < 4; ++r) {
          int m = wm*32 + mf*16 + l4*4 + r;
          float t  = __expf(2.0f * acc[mf][nf][r]);
          float th = 1.0f - __fdividef(2.0f, t + 1.0f);   // tanh, saturates correctly
          *(unsigned short*)(Albase + m*1024 + n2) = f2bf(th);
        }
      }
    }
  };
  write_a();   // iteration 1: a1 = tanh(c + b)

  // ---- iterations 2..15: a = tanh(a @ Ws + C)  (K=512, 16 K-steps) ----
  auto stageW = [&](unsigned char* lds, const unsigned char* g0) {
    for (int c = tid; c < 2048; c += THREADS) {
      int d = c << 4;
      gload16(g0 + (size_t)(d >> 6) * 1024 + (d & 63), lds + d);
    }
  };
#pragma unroll 1
  for (int it = 0; it < 14; ++it) {
    stageW(Tbuf0, gWs);
#pragma unroll
    for (int mf = 0; mf < 2; ++mf)
#pragma unroll
      for (int nf = 0; nf < 8; ++nf)
        acc[mf][nf] = cfrag[mf][nf];
#pragma unroll 1
    for (int ks = 0; ks < 16; ++ks) {
      __syncthreads();
      unsigned char* curb = (ks & 1) ? Tbuf1 : Tbuf0;
      if (ks < 15) stageW((ks & 1) ? Tbuf0 : Tbuf1, gWs + (ks + 1) * 64);
      int akb = ks * 64 + l4 * 16;
      bf16x8 a0 = *(const bf16x8*)(Albase + (wm*32      + l15) * 1024 + akb);
      bf16x8 a1 = *(const bf16x8*)(Albase + (wm*32 + 16 + l15) * 1024 + akb);
#pragma unroll
      for (int nf = 0; nf < 8; ++nf) {
        bf16x8 bb = *(const bf16x8*)(curb + (wn*128 + nf*16 + l15) * 64 + l4 * 16);
        acc[0][nf] = __builtin_amdgcn_mfma_f32_16x16x32_bf16(a0, bb, acc[0][nf], 0, 0, 0);
        acc[1][nf] = __builtin_amdgcn_mfma_f32_16x16x32_bf16(a1, bb, acc[1][nf], 0, 0, 0);
      }
    }
    __syncthreads();
    write_a();
  }

  // ---- phase C: y = a @ w_out^T + w_out_b, split w_out (ah*Wh + ah*Wl) ----
  f32x4 oacc[2][4];
#pragma unroll
  for (int nf = 0; nf < 4; ++nf) {
    float wob = w_out_b[wn*64 + nf*16 + l15];
    f32x4 v = {wob, wob, wob, wob};
    oacc[0][nf] = v;
    oacc[1][nf] = v;
  }
  // double-buffered: buf = [Wh chunk 16KB][Wl chunk 16KB]
  auto stageOut = [&](int ks, unsigned char* buf) {
    for (int c = tid; c < 1024; c += THREADS) {
      int d = c << 4; int row = d >> 6; int col = d & 63;
      size_t g = (size_t)row * 1024 + (size_t)ks * 64 + col;
      gload16(gWoutH + g, buf + d);
      gload16(gWoutL + g, buf + 16384 + d);
    }
  };
  stageOut(0, Tbuf0);
#pragma unroll 1
  for (int ks = 0; ks < 16; ++ks) {
    __syncthreads();
    unsigned char* cur = (ks & 1) ? Tbuf1 : Tbuf0;
    if (ks < 15) stageOut(ks + 1, (ks & 1) ? Tbuf0 : Tbuf1);
    int akb = ks * 64 + l4 * 16;
    bf16x8 a0 = *(const bf16x8*)(Albase + (wm*32      + l15) * 1024 + akb);
    bf16x8 a1 = *(const bf16x8*)(Albase + (wm*32 + 16 + l15) * 1024 + akb);
#pragma unroll
    for (int nf = 0; nf < 4; ++nf) {
      int bp = (wn*64 + nf*16 + l15) * 64 + l4 * 16;
      bf16x8 bh = *(const bf16x8*)(cur + bp);
      bf16x8 bl = *(const bf16x8*)(cur + 16384 + bp);
      oacc[0][nf] = __builtin_amdgcn_mfma_f32_16x16x32_bf16(a0, bh, oacc[0][nf], 0, 0, 0);
      oacc[0][nf] = __builtin_amdgcn_mfma_f32_16x16x32_bf16(a0, bl, oacc[0][nf], 0, 0, 0);
      oacc[1][nf] = __builtin_amdgcn_mfma_f32_16x16x32_bf16(a1, bh, oacc[1][nf], 0, 0, 0);
      oacc[1][nf] = __builtin_amdgcn_mfma_f32_16x16x32_bf16(a1, bl, oacc[1][nf], 0, 0, 0);
    }
  }

  const size_t HALF = (size_t)8 * 4096 * 256;
#pragma unroll
  for (int mf = 0; mf < 2; ++mf) {
#pragma unroll
    for (int nf = 0; nf < 4; ++nf) {
      int j = wn*64 + nf*16 + l15;
#pragma unroll
      for (int r = 0; r < 4; ++r) {
        int m = m0 + wm*32 + mf*16 + l4*4 + r;
        size_t idx = (size_t)m * 256 + j;
        float y = oacc[mf][nf][r];
        out[idx]        = y;
        out[HALF + idx] = x[idx] - y;
      }
    }
  }
}

extern "C" void kernel_launch(void* const* d_in, const int* in_sizes, int n_in,
                              void* d_out, int out_size, void* d_ws, size_t ws_size,
                              hipStream_t stream) {
  const float* x       = (const float*)d_in[0];
  const float* w_in_w  = (const float*)d_in[1];
  const float* w_in_b  = (const float*)d_in[2];
  const float* W       = (const float*)d_in[3];
  const float* b       = (const float*)d_in[4];
  const float* w_out_w = (const float*)d_in[5];
  const float* w_out_b = (const float*)d_in[6];
  float* out = (float*)d_out;
  unsigned char* ws = (unsigned char*)d_ws;

  int total = 512*512 + 512*256 + 256*512 + 512;
  prep_kernel<<<(total + 255) / 256, 256, 0, stream>>>(W, w_in_w, w_out_w, w_in_b, b, ws);
  attractor_kernel<<<512, THREADS, 0, stream>>>(x, ws, w_out_b, out);
}